// Round 5
// baseline (340.213 us; speedup 1.0000x reference)
//
#include <hip/hip_runtime.h>

#define EPSBN 1e-5f

typedef _Float16 f16;
typedef _Float16 f16x8 __attribute__((ext_vector_type(8)));
typedef _Float16 f16x4 __attribute__((ext_vector_type(4)));
typedef _Float16 f16x2 __attribute__((ext_vector_type(2)));
typedef float    f32x4 __attribute__((ext_vector_type(4)));

__device__ inline unsigned int pack2(float a, float b) {
    union { f16x2 h; unsigned int u; } cv;
    cv.h[0] = (f16)a; cv.h[1] = (f16)b;
    return cv.u;
}
__device__ inline f16x4 hmax4(f16x4 a, f16x4 b) {
    f16x4 r;
    #pragma unroll
    for (int i = 0; i < 4; ++i) r[i] = a[i] > b[i] ? a[i] : b[i];
    return r;
}
__device__ inline f16x8 relu8(f16x8 v) {
    f16x8 r;
    #pragma unroll
    for (int i = 0; i < 8; ++i) r[i] = v[i] > (f16)0.f ? v[i] : (f16)0.f;
    return r;
}

// ---------------------------------------------------------------------------
// wprep: weights -> f16.  fc1w [0,32768) ; w1 [32768,40960) ;
// w2 as [tau][o][i] [40960,53248) ; w3 [53248,61440)
// ---------------------------------------------------------------------------
__global__ void wprep_kernel(const float* __restrict__ fc1w,
                             const float* __restrict__ w1,
                             const float* __restrict__ w2,
                             const float* __restrict__ w3,
                             f16* __restrict__ dst) {
    const int i = blockIdx.x * 256 + threadIdx.x;   // 61440 total
    float v;
    if (i < 32768)      v = fc1w[i];
    else if (i < 40960) v = w1[i - 32768];
    else if (i < 53248) {
        const int j = i - 40960, tau = j >> 12, rest = j & 4095;
        v = w2[rest * 3 + tau];
    } else              v = w3[i - 53248];
    dst[i] = (f16)v;
}

// ---------------------------------------------------------------------------
// fc1 v2: single-pass K=256, coalesced staging, 16 loads in flight/thread.
// Tile 64p x 128o.  image = blockIdx & 7 (XCD-pinned).
// LDS: feature transposed [p][k-pair] u32, row stride 130 (b64 frag reads
// conflict-free; staging writes ~4-way, negligible).
// ---------------------------------------------------------------------------
__global__ __launch_bounds__(256, 4)
void fc1_mfma(const float* __restrict__ feat,   // [8][256][16384]
              const f16*   __restrict__ w16,    // [128][256] f16
              const float* __restrict__ bias,   // [128]
              f16*         __restrict__ xmap) { // [8][16384][128]
    __shared__ unsigned int ldsu[64 * 130];     // 33280 B; epilogue overlays

    const int tid  = threadIdx.x;
    const int wv   = tid >> 6, lane = tid & 63;
    const int n16  = lane & 15, quad = lane >> 4;
    const int b    = blockIdx.x & 7;             // XCD swizzle
    const int p0   = (blockIdx.x >> 3) * 64;
    const int lane16 = tid & 15;                 // float4 index along p
    const int r2     = tid >> 4;                 // row-pair group (0..15)

    // ---- stage: 16 coalesced float4 loads, pack fp32->f16 pairs ----
    const float* fbase = feat + ((size_t)b << 22) + p0 + lane16 * 4;
    #pragma unroll
    for (int i = 0; i < 8; ++i) {
        const int kp = r2 + 16 * i;              // k-pair 0..127
        const float* ra = fbase + ((size_t)(2 * kp) << 14);
        const float4 f4a = *(const float4*)ra;
        const float4 f4b = *(const float4*)(ra + 16384);
        ldsu[(lane16 * 4 + 0) * 130 + kp] = pack2(f4a.x, f4b.x);
        ldsu[(lane16 * 4 + 1) * 130 + kp] = pack2(f4a.y, f4b.y);
        ldsu[(lane16 * 4 + 2) * 130 + kp] = pack2(f4a.z, f4b.z);
        ldsu[(lane16 * 4 + 3) * 130 + kp] = pack2(f4a.w, f4b.w);
    }
    __syncthreads();

    // ---- MFMA: wave wv -> p-rows wv*16+n16; all 8 o-tiles; K=256 ----
    f32x4 acc[8];
    #pragma unroll
    for (int nt = 0; nt < 8; ++nt) acc[nt] = (f32x4){0.f, 0.f, 0.f, 0.f};

    const unsigned int* arow = ldsu + (wv * 16 + n16) * 130;
    #pragma unroll
    for (int ks = 0; ks < 8; ++ks) {
        const int c = ks * 16 + quad * 4;
        union { f16x8 v; f16x4 h[2]; } af;
        af.h[0] = *(const f16x4*)&arow[c];
        af.h[1] = *(const f16x4*)&arow[c + 2];
        #pragma unroll
        for (int nt = 0; nt < 8; ++nt) {
            const f16x8 bf = *(const f16x8*)&w16[(size_t)(nt * 16 + n16) * 256
                                                 + ks * 32 + quad * 8];
            acc[nt] = __builtin_amdgcn_mfma_f32_16x16x32_f16(af.v, bf, acc[nt], 0, 0, 0);
        }
    }
    __syncthreads();

    // ---- epilogue via LDS: [p][o] f16, stride 136; coalesced row stores ----
    f16* ep = (f16*)ldsu;
    #pragma unroll
    for (int nt = 0; nt < 8; ++nt) {
        const int o = nt * 16 + n16;
        const float bo = bias[o];
        #pragma unroll
        for (int r = 0; r < 4; ++r)
            ep[(wv * 16 + quad * 4 + r) * 136 + o] = (f16)(acc[nt][r] + bo);
    }
    __syncthreads();

    #pragma unroll
    for (int it = 0; it < 4; ++it) {
        const int u = tid + 256 * it;
        const int row = u >> 4, cg = u & 15;
        const float4 v = *(const float4*)&ep[row * 136 + cg * 8];
        *(float4*)&xmap[(((size_t)((b << 14) + p0 + row)) << 7) + cg * 8] = v;
    }
}

// ---------------------------------------------------------------------------
// loi: 8 lines/block, image = blockIdx & 7 (XCD-pinned).  Packed-f16 sampling
// -> xp[64n][128c] f16 -> conv1/conv2/conv3 MFMA -> residual+relu+fc2.
// ---------------------------------------------------------------------------
__global__ __launch_bounds__(256)
void loi_kernel(const f16*   __restrict__ x,       // [8][16384][128] f16
                const float* __restrict__ lines,
                const f16*   __restrict__ wsp,
                const float* __restrict__ bn1g, const float* __restrict__ bn1b,
                const float* __restrict__ bn1m, const float* __restrict__ bn1v,
                const float* __restrict__ b1,
                const float* __restrict__ bn2g, const float* __restrict__ bn2b,
                const float* __restrict__ bn2m, const float* __restrict__ bn2v,
                const float* __restrict__ b2,
                const float* __restrict__ bn3g, const float* __restrict__ bn3b,
                const float* __restrict__ bn3m, const float* __restrict__ bn3v,
                const float* __restrict__ b3,
                const float* __restrict__ fc2w, const float* __restrict__ fc2b,
                float* __restrict__ out) {
    __shared__ f16 xp[64][136];                       // 17408 B
    __shared__ alignas(16) union {
        struct { int toff[256][4]; f16 twgt[256][4]; } tp;     // 6144 B
        struct { f16 h1[80][72]; f16 h2[64][72]; } cv;         // 20736 B
    } u;
    __shared__ f16 s1h[128], t1h[128];                // 512 B
    __shared__ float s2f[64], t2f[64], s3f[64], t3f[64], b1f[64], b2f[64];
    __shared__ float b3f[128];
    __shared__ float wsum[4][8];

    const f16* w1f16 = wsp + 32768;
    const f16* w2f16 = wsp + 40960;
    const f16* w3f16 = wsp + 53248;

    const int tid  = threadIdx.x;
    const int wv   = tid >> 6, lane = tid & 63;
    const int n16  = lane & 15, quad = lane >> 4;
    const int img  = blockIdx.x & 7;                  // XCD swizzle
    const int mblk = blockIdx.x >> 3;                 // 0..255 within image

    // ---- LUTs ----
    if (tid < 128) {
        const float s = bn1g[tid] * rsqrtf(bn1v[tid] + EPSBN);
        s1h[tid] = (f16)s; t1h[tid] = (f16)(bn1b[tid] - bn1m[tid] * s);
    }
    if (tid < 64) {
        const float s = bn2g[tid] * rsqrtf(bn2v[tid] + EPSBN);
        s2f[tid] = s; t2f[tid] = bn2b[tid] - bn2m[tid] * s;
        b1f[tid] = b1[tid];
    } else if (tid < 128) {
        const int c = tid - 64;
        const float s = bn3g[c] * rsqrtf(bn3v[c] + EPSBN);
        s3f[c] = s; t3f[c] = bn3b[c] - bn3m[c] * s;
        b2f[c] = b2[c];
    } else {
        b3f[tid - 128] = b3[tid - 128];
    }

    // ---- interp tuples: one per (line, pt) ----
    {
        const int li = tid >> 5, pt = tid & 31;
        const int gl = img * 2048 + mblk * 8 + li;
        const float4 ln = *(const float4*)&lines[gl * 4];
        const float lam = (float)pt * (1.0f / 31.0f);
        const float px = ln.x * lam + ln.z * (1.f - lam) - 0.5f;
        const float py = ln.y * lam + ln.w * (1.f - lam) - 0.5f;
        const float px0 = fminf(fmaxf(floorf(px), 0.f), 127.f);
        const float py0 = fminf(fmaxf(floorf(py), 0.f), 127.f);
        const float px1 = fminf(px0 + 1.f, 127.f);
        const float py1 = fminf(py0 + 1.f, 127.f);
        const int ix0 = (int)px0, iy0 = (int)py0;
        const int ix1 = (int)px1, iy1 = (int)py1;
        u.tp.toff[tid][0] = (((ix0 << 7) + iy0) << 7);
        u.tp.toff[tid][1] = (((ix1 << 7) + iy0) << 7);
        u.tp.toff[tid][2] = (((ix0 << 7) + iy1) << 7);
        u.tp.toff[tid][3] = (((ix1 << 7) + iy1) << 7);
        const float wx1 = px1 - px, wx0 = px - px0;
        const float wy1 = py1 - py, wy0 = py - py0;
        u.tp.twgt[tid][0] = (f16)(wx1 * wy1); u.tp.twgt[tid][1] = (f16)(wx0 * wy1);
        u.tp.twgt[tid][2] = (f16)(wx1 * wy0); u.tp.twgt[tid][3] = (f16)(wx0 * wy0);
    }
    __syncthreads();   // B1

    // ---- sampling + maxpool, packed f16: lane -> 4 channels, half-wave -> line ----
    {
        const int h = lane >> 5, j = lane & 31;     // line parity, channel group
        const int li = wv * 2 + h;
        const f16* xbh = x + (((size_t)img) << 21) + 4 * j;
        #pragma unroll
        for (int t = 0; t < 8; ++t) {
            f16x4 m = {(f16)(-60000.f), (f16)(-60000.f), (f16)(-60000.f), (f16)(-60000.f)};
            #pragma unroll
            for (int s = 0; s < 4; ++s) {
                const int combo = li * 32 + t * 4 + s;
                const int4  off = *(const int4*)&u.tp.toff[combo][0];
                const f16x4 tw  = *(const f16x4*)&u.tp.twgt[combo][0];
                const f16x4 g00 = *(const f16x4*)(xbh + off.x);
                const f16x4 g10 = *(const f16x4*)(xbh + off.y);
                const f16x4 g01 = *(const f16x4*)(xbh + off.z);
                const f16x4 g11 = *(const f16x4*)(xbh + off.w);
                const f16x4 w0 = {tw[0], tw[0], tw[0], tw[0]};
                const f16x4 w1v = {tw[1], tw[1], tw[1], tw[1]};
                const f16x4 w2v = {tw[2], tw[2], tw[2], tw[2]};
                const f16x4 w3v = {tw[3], tw[3], tw[3], tw[3]};
                f16x4 v = g00 * w0 + g10 * w1v + g01 * w2v + g11 * w3v;
                m = hmax4(m, v);
            }
            *(f16x4*)&xp[li * 8 + t][4 * j] = m;
        }
    }
    __syncthreads();   // B2 (tuples dead; xp ready)

    // ---- zero h1 guard rows ----
    {
        const int r = tid >> 4, seg = tid & 15;
        const int row = (r >> 1) * 10 + (r & 1) * 9;
        *(unsigned long long*)&u.cv.h1[row][seg * 4] = 0ull;
    }

    // ---- conv1 + fused bn1/relu (packed f16) ----
    {
        const int o_lane = wv * 16 + n16;
        f32x4 acc1[4];
        #pragma unroll
        for (int nt = 0; nt < 4; ++nt) acc1[nt] = (f32x4){0.f, 0.f, 0.f, 0.f};
        #pragma unroll
        for (int ks = 0; ks < 4; ++ks) {
            const int k = ks * 32 + quad * 8;
            const f16x8 a  = *(const f16x8*)&w1f16[o_lane * 128 + k];
            const f16x8 s8 = *(const f16x8*)&s1h[k];
            const f16x8 t8 = *(const f16x8*)&t1h[k];
            #pragma unroll
            for (int nt = 0; nt < 4; ++nt) {
                const f16x8 raw = *(const f16x8*)&xp[nt * 16 + n16][k];
                const f16x8 bf = relu8(raw * s8 + t8);
                acc1[nt] = __builtin_amdgcn_mfma_f32_16x16x32_f16(a, bf, acc1[nt], 0, 0, 0);
            }
        }
        #pragma unroll
        for (int nt = 0; nt < 4; ++nt) {
            const int n = nt * 16 + n16;
            const int nprow = (n >> 3) * 10 + (n & 7) + 1;
            #pragma unroll
            for (int r = 0; r < 4; ++r) {
                const int o = wv * 16 + quad * 4 + r;
                const float v = fmaxf((acc1[nt][r] + b1f[o]) * s2f[o] + t2f[o], 0.f);
                u.cv.h1[nprow][o] = (f16)v;
            }
        }
    }
    __syncthreads();   // B3

    // ---- conv2: 3 shifted [64x64] matmuls ----
    {
        const int o_lane = wv * 16 + n16;
        f32x4 acc2[4];
        #pragma unroll
        for (int nt = 0; nt < 4; ++nt) acc2[nt] = (f32x4){0.f, 0.f, 0.f, 0.f};
        #pragma unroll
        for (int d = 0; d < 3; ++d) {
            const f16* A2 = w2f16 + d * 4096;
            #pragma unroll
            for (int ks = 0; ks < 2; ++ks) {
                const int k = ks * 32 + quad * 8;
                const f16x8 a = *(const f16x8*)&A2[o_lane * 64 + k];
                #pragma unroll
                for (int nt = 0; nt < 4; ++nt) {
                    const int n = nt * 16 + n16;
                    const int row = (n >> 3) * 10 + (n & 7) + d;
                    const f16x8 bf = *(const f16x8*)&u.cv.h1[row][k];
                    acc2[nt] = __builtin_amdgcn_mfma_f32_16x16x32_f16(a, bf, acc2[nt], 0, 0, 0);
                }
            }
        }
        #pragma unroll
        for (int nt = 0; nt < 4; ++nt) {
            const int n = nt * 16 + n16;
            #pragma unroll
            for (int r = 0; r < 4; ++r) {
                const int o = wv * 16 + quad * 4 + r;
                const float v = fmaxf((acc2[nt][r] + b2f[o]) * s3f[o] + t3f[o], 0.f);
                u.cv.h2[n][o] = (f16)v;
            }
        }
    }
    __syncthreads();   // B4

    // ---- conv3 + residual + relu + fc2 ----
    {
        const int col = n16 & 7, obase = wv * 16 + quad * 4;
        float fcv[2][4];
        #pragma unroll
        for (int h = 0; h < 2; ++h)
            #pragma unroll
            for (int r = 0; r < 4; ++r)
                fcv[h][r] = fc2w[(h * 64 + obase + r) * 8 + col];

        f32x4 acc3[2][4];
        #pragma unroll
        for (int h = 0; h < 2; ++h)
            #pragma unroll
            for (int nt = 0; nt < 4; ++nt) acc3[h][nt] = (f32x4){0.f, 0.f, 0.f, 0.f};
        #pragma unroll
        for (int ks = 0; ks < 2; ++ks) {
            const int k = ks * 32 + quad * 8;
            const f16x8 a0 = *(const f16x8*)&w3f16[(wv * 16 + n16) * 64 + k];
            const f16x8 a1 = *(const f16x8*)&w3f16[(64 + wv * 16 + n16) * 64 + k];
            #pragma unroll
            for (int nt = 0; nt < 4; ++nt) {
                const f16x8 bf = *(const f16x8*)&u.cv.h2[nt * 16 + n16][k];
                acc3[0][nt] = __builtin_amdgcn_mfma_f32_16x16x32_f16(a0, bf, acc3[0][nt], 0, 0, 0);
                acc3[1][nt] = __builtin_amdgcn_mfma_f32_16x16x32_f16(a1, bf, acc3[1][nt], 0, 0, 0);
            }
        }
        float part[4] = {0.f, 0.f, 0.f, 0.f};
        #pragma unroll
        for (int h = 0; h < 2; ++h) {
            const float4 bq = *(const float4*)&b3f[h * 64 + obase];
            const float bqa[4] = {bq.x, bq.y, bq.z, bq.w};
            #pragma unroll
            for (int nt = 0; nt < 4; ++nt) {
                const int n = nt * 16 + n16;
                const f16x4 rx = *(const f16x4*)&xp[n][h * 64 + obase];
                float p = 0.f;
                #pragma unroll
                for (int r = 0; r < 4; ++r) {
                    float v = acc3[h][nt][r] + bqa[r] + (float)rx[r];
                    v = fmaxf(v, 0.f);
                    p += v * fcv[h][r];
                }
                part[nt] += p;
            }
        }
        #pragma unroll
        for (int off_i = 0; off_i < 5; ++off_i) {
            const int off = (int[]){1, 2, 4, 16, 32}[off_i];
            part[0] += __shfl_xor(part[0], off, 64);
            part[1] += __shfl_xor(part[1], off, 64);
            part[2] += __shfl_xor(part[2], off, 64);
            part[3] += __shfl_xor(part[3], off, 64);
        }
        if ((lane & 55) == 0) {          // lanes 0 and 8
            const int par = (lane >> 3) & 1;
            wsum[wv][0 + par] = part[0];
            wsum[wv][2 + par] = part[1];
            wsum[wv][4 + par] = part[2];
            wsum[wv][6 + par] = part[3];
        }
    }
    __syncthreads();   // B5

    if (tid < 8) {
        const float s = wsum[0][tid] + wsum[1][tid] + wsum[2][tid] + wsum[3][tid];
        out[img * 2048 + mblk * 8 + tid] = s + fc2b[0];
    }
}

// ---------------------------------------------------------------------------
extern "C" void kernel_launch(void* const* d_in, const int* in_sizes, int n_in,
                              void* d_out, int out_size, void* d_ws, size_t ws_size,
                              hipStream_t stream) {
    const float* feature = (const float*)d_in[0];
    const float* lines   = (const float*)d_in[1];
    const float* fc1_w   = (const float*)d_in[2];
    const float* fc1_b   = (const float*)d_in[3];
    const float* bn1g    = (const float*)d_in[4];
    const float* bn1b    = (const float*)d_in[5];
    const float* bn1m    = (const float*)d_in[6];
    const float* bn1v    = (const float*)d_in[7];
    const float* w1      = (const float*)d_in[8];
    const float* b1      = (const float*)d_in[9];
    const float* bn2g    = (const float*)d_in[10];
    const float* bn2b    = (const float*)d_in[11];
    const float* bn2m    = (const float*)d_in[12];
    const float* bn2v    = (const float*)d_in[13];
    const float* w2      = (const float*)d_in[14];
    const float* b2      = (const float*)d_in[15];
    const float* bn3g    = (const float*)d_in[16];
    const float* bn3b    = (const float*)d_in[17];
    const float* bn3m    = (const float*)d_in[18];
    const float* bn3v    = (const float*)d_in[19];
    const float* w3      = (const float*)d_in[20];
    const float* b3      = (const float*)d_in[21];
    const float* fc2w    = (const float*)d_in[22];
    const float* fc2b    = (const float*)d_in[23];

    f16* xmap = (f16*)d_ws;                                      // 32 MiB
    f16* wsp  = (f16*)((char*)d_ws + (size_t)32 * 1024 * 1024);  // 120 KiB

    wprep_kernel<<<240, 256, 0, stream>>>(fc1_w, w1, w2, w3, wsp);
    fc1_mfma<<<2048, 256, 0, stream>>>(feature, wsp, fc1_b, xmap);
    loi_kernel<<<2048, 256, 0, stream>>>(xmap, lines, wsp,
                                         bn1g, bn1b, bn1m, bn1v, b1,
                                         bn2g, bn2b, bn2m, bn2v, b2,
                                         bn3g, bn3b, bn3m, bn3v, b3,
                                         fc2w, fc2b, (float*)d_out);
}